// Round 2
// baseline (2465.475 us; speedup 1.0000x reference)
//
#include <hip/hip_runtime.h>
#include <hip/hip_cooperative_groups.h>

namespace cg = cooperative_groups;

#define H 512
#define W 512
#define S (H*W)            // 262144 points per plane
#define BS 16
#define CH 3
#define NP (BS*CH)         // 48 planes
#define WCS ((H-1)*W)      // weights_col plane stride
#define WRS (H*(W-1))      // weights_row plane stride
#define MAXIT 100
#define BLOCK 256
#define EPSF 158.32967f    // (1e-6 * 16*3*512*512)^2

__device__ __forceinline__ float aload(const float* p) {
  return __hip_atomic_load(p, __ATOMIC_RELAXED, __HIP_MEMORY_SCOPE_AGENT);
}

__device__ __forceinline__ float nan2num(float v) {
  if (__builtin_isnan(v)) return 0.0f;
  if (__builtin_isinf(v)) return v > 0.0f ? 3.4028235e38f : -3.4028235e38f;
  return v;
}

__device__ __forceinline__ float wave_sum(float v) {
#pragma unroll
  for (int off = 32; off > 0; off >>= 1) v += __shfl_xor(v, off, 64);
  return v;
}

// Persistent cooperative CG. Thread owns spatial points {g0, g0+gsz, ...} in
// all 48 planes. x (=d_out), p, r live in global (L3-resident). Reductions:
// wave shuffle -> LDS -> 48 atomics/block. Scalars re-read with agent-scope
// atomic loads (cross-XCD coherent), staged in LDS.
__global__ void __launch_bounds__(BLOCK, 4)
cg_kernel(const float* __restrict__ Bp, const float* __restrict__ WC,
          const float* __restrict__ WR, float* __restrict__ X,
          float* __restrict__ P, float* __restrict__ R,
          float* __restrict__ rr, float* __restrict__ pap)
{
  cg::grid_group grid = cg::this_grid();
  const int tid = (int)threadIdx.x;
  const int gsz = (int)gridDim.x * BLOCK;
  const int g0 = (int)blockIdx.x * BLOCK + tid;
  const int lane = tid & 63, wid = tid >> 6;
  __shared__ float red[BLOCK / 64][NP];
  __shared__ float sc[NP];

  // ---- zero reduction accumulators (ws is re-poisoned every call) ----
  for (int i = g0; i < (MAXIT + 1) * NP; i += gsz) { rr[i] = 0.f; pap[i] = 0.f; }
  grid.sync();

  // ---- Phase 0: x = B; r = p = B - A*B; rr0 ----
  for (int b = 0; b < BS; ++b) {
    const float* wcb = WC + (size_t)b * WCS;
    const float* wrb = WR + (size_t)b * WRS;
    float a0 = 0.f, a1 = 0.f, a2 = 0.f;
    for (int t = g0; t < S; t += gsz) {
      const int y = t >> 9, xc = t & (W - 1);
      const bool up = y > 0, dn = y < H - 1, lt = xc > 0, rt = xc < W - 1;
      const float wu = up ? wcb[t - W] : 0.f;            // col[b][y-1][x]
      const float wd = dn ? wcb[t] : 0.f;                // col[b][y][x]
      const float wl = lt ? wrb[y * (W - 1) + xc - 1] : 0.f;
      const float wrv = rt ? wrb[y * (W - 1) + xc] : 0.f;
      const float kv = 1.f + wu + wd + wl + wrv;
#pragma unroll
      for (int c = 0; c < CH; ++c) {
        const int j = b * CH + c;
        const float* bp = Bp + (size_t)j * S;
        const float pc = bp[t];
        const float pu = up ? bp[t - W] : 0.f;
        const float pd = dn ? bp[t + W] : 0.f;
        const float pl = lt ? bp[t - 1] : 0.f;
        const float pr = rt ? bp[t + 1] : 0.f;
        const float av = kv * pc - wu * pu - wd * pd - wl * pl - wrv * pr;
        const float r0 = pc - av;
        X[(size_t)j * S + t] = pc;
        P[(size_t)j * S + t] = r0;
        R[(size_t)j * S + t] = r0;
        const float q = r0 * r0;
        if (c == 0) a0 += q; else if (c == 1) a1 += q; else a2 += q;
      }
    }
    const float s0 = wave_sum(a0), s1 = wave_sum(a1), s2 = wave_sum(a2);
    if (lane == 0) {
      red[wid][b * CH + 0] = s0; red[wid][b * CH + 1] = s1; red[wid][b * CH + 2] = s2;
    }
  }
  __syncthreads();
  if (tid < NP) {
    const int g = (tid + (int)blockIdx.x) % NP;
    atomicAdd(&rr[g], red[0][g] + red[1][g] + red[2][g] + red[3][g]);
  }
  grid.sync();

  // ---- CG loop ----
  for (int k = 1; k <= MAXIT; ++k) {
    if (k >= 2) {  // reference: exit when sum(rr_new) < eps
      if (tid < NP) sc[tid] = aload(&rr[(size_t)(k - 1) * NP + tid]);
      __syncthreads();
      float tot = 0.f;
#pragma unroll
      for (int g = 0; g < NP; ++g) tot += sc[g];
      if (tot < EPSF) break;  // uniform decision (identical order, coherent loads)
    }

    // -- Phase A: pAp = <p, A p> --
    for (int b = 0; b < BS; ++b) {
      const float* wcb = WC + (size_t)b * WCS;
      const float* wrb = WR + (size_t)b * WRS;
      float a0 = 0.f, a1 = 0.f, a2 = 0.f;
      for (int t = g0; t < S; t += gsz) {
        const int y = t >> 9, xc = t & (W - 1);
        const bool up = y > 0, dn = y < H - 1, lt = xc > 0, rt = xc < W - 1;
        const float wu = up ? wcb[t - W] : 0.f;
        const float wd = dn ? wcb[t] : 0.f;
        const float wl = lt ? wrb[y * (W - 1) + xc - 1] : 0.f;
        const float wrv = rt ? wrb[y * (W - 1) + xc] : 0.f;
        const float kv = 1.f + wu + wd + wl + wrv;
#pragma unroll
        for (int c = 0; c < CH; ++c) {
          const int j = b * CH + c;
          const float* pp = P + (size_t)j * S;
          const float pc = pp[t];
          const float pu = up ? pp[t - W] : 0.f;
          const float pd = dn ? pp[t + W] : 0.f;
          const float pl = lt ? pp[t - 1] : 0.f;
          const float pr = rt ? pp[t + 1] : 0.f;
          const float apv = kv * pc - wu * pu - wd * pd - wl * pl - wrv * pr;
          const float q = pc * apv;
          if (c == 0) a0 += q; else if (c == 1) a1 += q; else a2 += q;
        }
      }
      const float s0 = wave_sum(a0), s1 = wave_sum(a1), s2 = wave_sum(a2);
      if (lane == 0) {
        red[wid][b * CH + 0] = s0; red[wid][b * CH + 1] = s1; red[wid][b * CH + 2] = s2;
      }
    }
    __syncthreads();
    if (tid < NP) {
      const int g = (tid + (int)blockIdx.x) % NP;
      atomicAdd(&pap[(size_t)k * NP + g],
                red[0][g] + red[1][g] + red[2][g] + red[3][g]);
    }
    grid.sync();

    // -- Phase B: a = rr/pAp; x += a p; r -= a (A p) [recomputed]; rr_new --
    if (tid < NP)
      sc[tid] = nan2num(aload(&rr[(size_t)(k - 1) * NP + tid]) /
                        aload(&pap[(size_t)k * NP + tid]));
    __syncthreads();
    for (int b = 0; b < BS; ++b) {
      const float* wcb = WC + (size_t)b * WCS;
      const float* wrb = WR + (size_t)b * WRS;
      float a0 = 0.f, a1 = 0.f, a2 = 0.f;
      for (int t = g0; t < S; t += gsz) {
        const int y = t >> 9, xc = t & (W - 1);
        const bool up = y > 0, dn = y < H - 1, lt = xc > 0, rt = xc < W - 1;
        const float wu = up ? wcb[t - W] : 0.f;
        const float wd = dn ? wcb[t] : 0.f;
        const float wl = lt ? wrb[y * (W - 1) + xc - 1] : 0.f;
        const float wrv = rt ? wrb[y * (W - 1) + xc] : 0.f;
        const float kv = 1.f + wu + wd + wl + wrv;
#pragma unroll
        for (int c = 0; c < CH; ++c) {
          const int j = b * CH + c;
          const float* pp = P + (size_t)j * S;
          const float a = sc[j];
          const float pc = pp[t];
          const float pu = up ? pp[t - W] : 0.f;
          const float pd = dn ? pp[t + W] : 0.f;
          const float pl = lt ? pp[t - 1] : 0.f;
          const float pr = rt ? pp[t + 1] : 0.f;
          const float apv = kv * pc - wu * pu - wd * pd - wl * pl - wrv * pr;
          X[(size_t)j * S + t] += a * pc;
          const float rv = R[(size_t)j * S + t] - a * apv;
          R[(size_t)j * S + t] = rv;
          const float q = rv * rv;
          if (c == 0) a0 += q; else if (c == 1) a1 += q; else a2 += q;
        }
      }
      const float s0 = wave_sum(a0), s1 = wave_sum(a1), s2 = wave_sum(a2);
      if (lane == 0) {
        red[wid][b * CH + 0] = s0; red[wid][b * CH + 1] = s1; red[wid][b * CH + 2] = s2;
      }
    }
    __syncthreads();
    if (tid < NP) {
      const int g = (tid + (int)blockIdx.x) % NP;
      atomicAdd(&rr[(size_t)k * NP + g],
                red[0][g] + red[1][g] + red[2][g] + red[3][g]);
    }
    grid.sync();

    // -- Phase C: b = rr_new/rr_old; p = r + b p --
    if (tid < NP)
      sc[tid] = nan2num(aload(&rr[(size_t)k * NP + tid]) /
                        aload(&rr[(size_t)(k - 1) * NP + tid]));
    __syncthreads();
    for (int t = g0; t < S; t += gsz) {
#pragma unroll
      for (int j = 0; j < NP; ++j) {
        const size_t o = (size_t)j * S + t;
        P[o] = R[o] + sc[j] * P[o];
      }
    }
    grid.sync();
  }
  // X (= d_out) holds the solution.
}

extern "C" void kernel_launch(void* const* d_in, const int* in_sizes, int n_in,
                              void* d_out, int out_size, void* d_ws, size_t ws_size,
                              hipStream_t stream) {
  const float* Bp = (const float*)d_in[0];
  const float* WC = (const float*)d_in[1];
  const float* WR = (const float*)d_in[2];
  float* X  = (float*)d_out;
  float* P  = (float*)d_ws;                      // 48*S floats (50 MB)
  float* R  = P + (size_t)NP * S;                // 48*S floats (50 MB)
  float* rr = R + (size_t)NP * S;                // (MAXIT+1)*48
  float* pap = rr + (size_t)(MAXIT + 1) * NP;    // (MAXIT+1)*48

  // Host-side occupancy query (enqueues nothing -> graph-capture safe).
  int dev = 0;
  hipGetDevice(&dev);
  int numCU = 0;
  if (hipDeviceGetAttribute(&numCU, hipDeviceAttributeMultiprocessorCount, dev)
      != hipSuccess || numCU < 1) numCU = 256;
  int perCU = 0;
  if (hipOccupancyMaxActiveBlocksPerMultiprocessor(&perCU, (const void*)cg_kernel,
                                                   BLOCK, 0) != hipSuccess || perCU < 1)
    perCU = 1;
  long long maxco = (long long)perCU * numCU;
  int gridb = 1024;                              // power of two so S % gsz == 0
  while (gridb > 1 && gridb > maxco) gridb >>= 1;

  void* args[] = { (void*)&Bp, (void*)&WC, (void*)&WR, (void*)&X,
                   (void*)&P, (void*)&R, (void*)&rr, (void*)&pap };
  hipLaunchCooperativeKernel((const void*)cg_kernel, dim3(gridb), dim3(BLOCK),
                             args, 0, stream);
}

// Round 3
// 721.307 us; speedup vs baseline: 3.4181x; 3.4181x over previous
//
#include <hip/hip_runtime.h>

#define H 512
#define W 512
#define S (H*W)            // 262144 points per plane
#define BS 16
#define CH 3
#define NP (BS*CH)         // 48 planes
#define WCS ((H-1)*W)      // weights_col per-batch stride (511*512)
#define WRS (H*(W-1))      // weights_row per-batch stride (512*511)
#define WRROW (W-1)        // weights_row row stride (511)

// One Chebyshev step: x_{k+1} = x_k + c1*(x_k - x_{k-1}) + c2*(b - A x_k)
// XS = x_k (read with 5-pt stencil), XO = x_{k-1} (pointwise), XD = x_{k+1}.
// XO and XD may alias (same buffer, same element per thread) -> no __restrict__
// on those two. Each thread: one float4 (4 pixels of one row) of one plane.
__global__ void __launch_bounds__(256)
cheb_step(const float* __restrict__ XS, const float* XO, float* XD,
          const float* __restrict__ Bp, const float* __restrict__ WC,
          const float* __restrict__ WR, float c1, float c2)
{
  const int j = blockIdx.y;                 // plane 0..47
  const int b = j / CH;                     // batch for weights
  const int t = (int)(blockIdx.x * blockDim.x + threadIdx.x) * 4;
  const int y = t >> 9, x = t & (W - 1);    // 4 pixels: (y, x..x+3), x%4==0

  const float* xs = XS + (size_t)j * S;
  const float* wc = WC + (size_t)b * WCS;
  const float* wrow = WR + (size_t)b * WRS + (size_t)y * WRROW;

  // aligned vector loads
  const float4 xc = *(const float4*)(xs + t);
  const float4 xo = *(const float4*)(XO + (size_t)j * S + t);
  const float4 bv = *(const float4*)(Bp + (size_t)j * S + t);
  float4 xu = make_float4(0.f, 0.f, 0.f, 0.f), xd = xu, wu = xu, wd = xu;
  if (y > 0)     { xu = *(const float4*)(xs + t - W);
                   wu = *(const float4*)(wc + t - W); }   // col[b][y-1][x..]
  if (y < H - 1) { xd = *(const float4*)(xs + t + W);
                   wd = *(const float4*)(wc + t); }       // col[b][y][x..]

  // shifted horizontal neighbors (x%4==0, row-local)
  const float xlm = (x > 0)     ? xs[t - 1] : 0.f;
  const float xrp = (x + 4 < W) ? xs[t + 4] : 0.f;
  const float4 xl = make_float4(xlm, xc.x, xc.y, xc.z);
  const float4 xr = make_float4(xc.y, xc.z, xc.w, xrp);

  // row-edge weights: left_i = wrow[x-1+i] (0 at x==0,i==0),
  //                   right_i = wrow[x+i]  (0 at x+i==W-1)
  const float wl0 = (x > 0) ? wrow[x - 1] : 0.f;
  const float w0 = wrow[x], w1 = wrow[x + 1], w2 = wrow[x + 2];
  const float w3 = (x + 3 < W - 1) ? wrow[x + 3] : 0.f;
  const float4 wl = make_float4(wl0, w0, w1, w2);
  const float4 wr = make_float4(w0, w1, w2, w3);

#define ELEM(f)                                                            \
  {                                                                        \
    const float kv = 1.f + wu.f + wd.f + wl.f + wr.f;                      \
    const float av = kv * xc.f - wu.f * xu.f - wd.f * xd.f                 \
                     - wl.f * xl.f - wr.f * xr.f;                          \
    out.f = xc.f + c1 * (xc.f - xo.f) + c2 * (bv.f - av);                  \
  }
  float4 out;
  ELEM(x) ELEM(y) ELEM(z) ELEM(w)
#undef ELEM

  *(float4*)(XD + (size_t)j * S + t) = out;
}

extern "C" void kernel_launch(void* const* d_in, const int* in_sizes, int n_in,
                              void* d_out, int out_size, void* d_ws, size_t ws_size,
                              hipStream_t stream) {
  const float* Bp = (const float*)d_in[0];
  const float* WC = (const float*)d_in[1];
  const float* WR = (const float*)d_in[2];
  float* Xout = (float*)d_out;     // holds x_j for even j (final x_K)
  float* bufA = (float*)d_ws;      // holds x_j for odd j   (50 MB)

  // Chebyshev on spectrum [1, 9]: theta=5, delta=4, sigma=theta/delta.
  // Rate 0.5/iter; K=16 -> ~2*2^-16 residual polynomial, way under threshold.
  const int K = 16;                       // even so x_K lands in d_out
  const float theta = 5.f, delta = 4.f, sigma = theta / delta;

  dim3 grid(S / 4 / 256, NP), block(256);

  // step 0: x1 = x0 + (1/theta) r0, x0 = B  -> bufA
  cheb_step<<<grid, block, 0, stream>>>(Bp, Bp, bufA, Bp, WC, WR,
                                        0.f, 1.f / theta);
  float rho_prev = 1.f / sigma;
  for (int i = 1; i < K; ++i) {
    const float rho = 1.f / (2.f * sigma - rho_prev);
    const float c1 = rho * rho_prev;
    const float c2 = 2.f * rho / delta;
    const float* xs = (i & 1) ? bufA : Xout;                      // x_i
    const float* xo = (i == 1) ? Bp : ((i & 1) ? Xout : bufA);    // x_{i-1}
    float* xd = (i & 1) ? Xout : bufA;                            // x_{i+1}
    cheb_step<<<grid, block, 0, stream>>>(xs, xo, xd, Bp, WC, WR, c1, c2);
    rho_prev = rho;
  }
}

// Round 4
// 471.860 us; speedup vs baseline: 5.2250x; 1.5286x over previous
//
#include <hip/hip_runtime.h>
#include <math.h>

#define H 512
#define W 512
#define S (H*W)            // 262144 points per plane
#define BS 16
#define CH 3
#define NP (BS*CH)         // 48 planes
#define WCS ((H-1)*W)      // weights_col per-batch stride (511*512)
#define WRS (H*(W-1))      // weights_row per-batch stride (512*511)
#define WRROW (W-1)        // weights_row row stride (511)
#define STRIP 16           // interior rows per block
#define EXTR (STRIP + 2)   // extended rows for step-1 (halo 1)
#define LROW 520           // LDS row stride in floats; data at cols 4..515

// Fused 2-step Chebyshev-node Richardson:
//   x1 = x0 + ta*(b - A x0)   on 18 extended rows -> LDS only
//   x2 = x1 + tb*(b - A x1)   on 16 interior rows -> global
// A = I + weighted 5-pt graph Laplacian; boundary edges have weight 0.
__global__ void __launch_bounds__(256)
cheb2(const float* __restrict__ XS, float* __restrict__ XD,
      const float* __restrict__ Bp, const float* __restrict__ WC,
      const float* __restrict__ WR, float ta, float tb)
{
  __shared__ float x1[EXTR][LROW];   // 37440 B -> 4 blocks/CU
  const int j  = blockIdx.y;         // plane 0..47
  const int bb = j / CH;             // batch index for weights
  const int y0 = blockIdx.x * STRIP;
  const int tid = (int)threadIdx.x;

  const float* xp  = XS + (size_t)j * S;
  const float* bp  = Bp + (size_t)j * S;
  const float* wcb = WC + (size_t)bb * WCS;
  const float* wrb = WR + (size_t)bb * WRS;

  // ---- step 1: x1 on rows y0-1 .. y0+16 (clamped) into LDS ----
  for (int idx = tid; idx < EXTR * 128; idx += 256) {
    const int rr = idx >> 7;             // 0..17
    const int c4 = (idx & 127) << 2;     // 0,4,...,508
    const int y  = y0 - 1 + rr;
    float4 out = make_float4(0.f, 0.f, 0.f, 0.f);
    if (y >= 0 && y < H) {
      const int t = y * W + c4;
      const float4 xc = *(const float4*)(xp + t);
      const float4 bv = *(const float4*)(bp + t);
      float4 xu = make_float4(0.f,0.f,0.f,0.f), xd = xu, wu = xu, wd = xu;
      if (y > 0)     { xu = *(const float4*)(xp + t - W);
                       wu = *(const float4*)(wcb + t - W); }
      if (y < H - 1) { xd = *(const float4*)(xp + t + W);
                       wd = *(const float4*)(wcb + t); }
      const float xlm = (c4 > 0)     ? xp[t - 1] : 0.f;
      const float xrp = (c4 + 4 < W) ? xp[t + 4] : 0.f;
      const float4 xl = make_float4(xlm, xc.x, xc.y, xc.z);
      const float4 xr = make_float4(xc.y, xc.z, xc.w, xrp);
      const float* wrow = wrb + (size_t)y * WRROW;
      const float wl0 = (c4 > 0) ? wrow[c4 - 1] : 0.f;
      const float w0 = wrow[c4], w1 = wrow[c4 + 1], w2 = wrow[c4 + 2];
      const float w3 = (c4 + 3 < W - 1) ? wrow[c4 + 3] : 0.f;
      const float4 wl = make_float4(wl0, w0, w1, w2);
      const float4 wr = make_float4(w0, w1, w2, w3);
#define ELEM(f) {                                                        \
        const float kv = 1.f + wu.f + wd.f + wl.f + wr.f;                \
        const float av = kv * xc.f - wu.f * xu.f - wd.f * xd.f           \
                         - wl.f * xl.f - wr.f * xr.f;                    \
        out.f = xc.f + ta * (bv.f - av); }
      ELEM(x) ELEM(y) ELEM(z) ELEM(w)
#undef ELEM
    }
    if (c4 == 0)   x1[rr][3]   = 0.f;    // left edge pad (finite, x weight 0)
    if (c4 == 508) x1[rr][516] = 0.f;    // right edge pad
    *(float4*)&x1[rr][4 + c4] = out;
  }
  __syncthreads();

  // ---- step 2: x2 on rows y0 .. y0+15 from LDS -> global ----
  for (int idx = tid; idx < STRIP * 128; idx += 256) {
    const int rr = idx >> 7;             // 0..15
    const int c4 = (idx & 127) << 2;
    const int y  = y0 + rr;
    const int l  = rr + 1;               // LDS row of x1[y]
    const int t  = y * W + c4;

    const float4 xc = *(const float4*)&x1[l][4 + c4];
    const float4 xu = *(const float4*)&x1[l - 1][4 + c4];  // zero row if y==0
    const float4 xd = *(const float4*)&x1[l + 1][4 + c4];  // zero row if y==H-1
    const float xlm = x1[l][3 + c4];
    const float xrp = x1[l][8 + c4];
    const float4 xl = make_float4(xlm, xc.x, xc.y, xc.z);
    const float4 xr = make_float4(xc.y, xc.z, xc.w, xrp);

    const float4 bv = *(const float4*)(bp + t);
    float4 wu = make_float4(0.f,0.f,0.f,0.f), wd = wu;
    if (y > 0)     wu = *(const float4*)(wcb + t - W);
    if (y < H - 1) wd = *(const float4*)(wcb + t);
    const float* wrow = wrb + (size_t)y * WRROW;
    const float wl0 = (c4 > 0) ? wrow[c4 - 1] : 0.f;
    const float w0 = wrow[c4], w1 = wrow[c4 + 1], w2 = wrow[c4 + 2];
    const float w3 = (c4 + 3 < W - 1) ? wrow[c4 + 3] : 0.f;
    const float4 wl = make_float4(wl0, w0, w1, w2);
    const float4 wr = make_float4(w0, w1, w2, w3);

    float4 out;
#define ELEM(f) {                                                        \
      const float kv = 1.f + wu.f + wd.f + wl.f + wr.f;                  \
      const float av = kv * xc.f - wu.f * xu.f - wd.f * xd.f             \
                       - wl.f * xl.f - wr.f * xr.f;                      \
      out.f = xc.f + tb * (bv.f - av); }
    ELEM(x) ELEM(y) ELEM(z) ELEM(w)
#undef ELEM
    *(float4*)(XD + (size_t)j * S + t) = out;
  }
}

extern "C" void kernel_launch(void* const* d_in, const int* in_sizes, int n_in,
                              void* d_out, int out_size, void* d_ws, size_t ws_size,
                              hipStream_t stream) {
  const float* Bp = (const float*)d_in[0];
  const float* WC = (const float*)d_in[1];
  const float* WR = (const float*)d_in[2];
  float* Xout = (float*)d_out;
  float* bufA = (float*)d_ws;          // 50 MB ping buffer

  // 16 Chebyshev nodes on [1,9] (theta=5, delta=4), Lebedev-Finogenov order
  // (conjugate pairs -> each fused kernel applies one stable pair).
  const int ord[16] = {1,16,8,9,4,13,5,12,2,15,7,10,3,14,6,11};
  float tau[16];
  for (int i = 0; i < 16; ++i) {
    const double lam = 5.0 + 4.0 * cos(M_PI * (2.0 * ord[i] - 1.0) / 32.0);
    tau[i] = (float)(1.0 / lam);
  }

  dim3 grid(H / STRIP, NP), block(256);
  const float* src = Bp;               // x_0 = B
  for (int i = 0; i < 8; ++i) {
    float* dst = (i & 1) ? Xout : bufA;            // i=7 -> Xout holds x_16
    cheb2<<<grid, block, 0, stream>>>(src, dst, Bp, WC, WR,
                                      tau[2 * i], tau[2 * i + 1]);
    src = dst;
  }
}

// Round 5
// 389.313 us; speedup vs baseline: 6.3329x; 1.2120x over previous
//
#include <hip/hip_runtime.h>
#include <math.h>

#define H 512
#define W 512
#define S (H*W)            // 262144 points per plane
#define BS 16
#define CH 3
#define NP (BS*CH)         // 48 planes
#define WCS ((H-1)*W)      // weights_col per-batch stride (511*512)
#define WRS (H*(W-1))      // weights_row per-batch stride (512*511)
#define WRROW (W-1)        // weights_row row stride (511)
#define STRIP 8            // interior rows per block
#define EXTR (STRIP + 2)   // extended rows for step-1 (halo 1)
#define LROW 520           // LDS row stride (floats); data at cols 4..515; 520*4%16==0

// Fused 2-step Chebyshev-node Richardson:
//   x1 = x0 + ta*(b - A x0)   on 10 extended rows -> LDS only
//   x2 = x1 + tb*(b - A x1)   on 8 interior rows  -> global
// A = I + weighted 5-pt graph Laplacian; boundary edges weight 0.
// LDS 20.8 KB -> 7 blocks/CU (~87% occupancy). All LDS accesses are aligned
// b128 (shifted neighbors via .w/.x of adjacent aligned float4) -> 0 conflicts.
__global__ void __launch_bounds__(256)
cheb2(const float* __restrict__ XS, float* __restrict__ XD,
      const float* __restrict__ Bp, const float* __restrict__ WC,
      const float* __restrict__ WR, float ta, float tb)
{
  __shared__ float x1[EXTR][LROW];   // 20800 B
  const int j  = blockIdx.y;         // plane 0..47
  const int bb = j / CH;             // batch index for weights
  const int y0 = blockIdx.x * STRIP;
  const int tid = (int)threadIdx.x;

  const float* xp  = XS + (size_t)j * S;
  const float* bp  = Bp + (size_t)j * S;
  const float* wcb = WC + (size_t)bb * WCS;
  const float* wrb = WR + (size_t)bb * WRS;

  // ---- step 1: x1 on rows y0-1 .. y0+8 (clamped) into LDS ----
  for (int idx = tid; idx < EXTR * 128; idx += 256) {
    const int rr = idx >> 7;             // 0..9
    const int c4 = (idx & 127) << 2;     // 0,4,...,508
    const int y  = y0 - 1 + rr;
    float4 out = make_float4(0.f, 0.f, 0.f, 0.f);
    if (y >= 0 && y < H) {
      const int t = y * W + c4;
      const float4 xc = *(const float4*)(xp + t);
      const float4 bv = *(const float4*)(bp + t);
      float4 xu = make_float4(0.f,0.f,0.f,0.f), xd = xu, wu = xu, wd = xu;
      if (y > 0)     { xu = *(const float4*)(xp + t - W);
                       wu = *(const float4*)(wcb + t - W); }
      if (y < H - 1) { xd = *(const float4*)(xp + t + W);
                       wd = *(const float4*)(wcb + t); }
      const float xlm = (c4 > 0)     ? xp[t - 1] : 0.f;
      const float xrp = (c4 + 4 < W) ? xp[t + 4] : 0.f;
      const float4 xl = make_float4(xlm, xc.x, xc.y, xc.z);
      const float4 xr = make_float4(xc.y, xc.z, xc.w, xrp);
      const float* wrow = wrb + (size_t)y * WRROW;
      const float wl0 = (c4 > 0) ? wrow[c4 - 1] : 0.f;
      const float w0 = wrow[c4], w1 = wrow[c4 + 1], w2 = wrow[c4 + 2];
      const float w3 = (c4 + 3 < W - 1) ? wrow[c4 + 3] : 0.f;
      const float4 wl = make_float4(wl0, w0, w1, w2);
      const float4 wr = make_float4(w0, w1, w2, w3);
#define ELEM(f) {                                                        \
        const float kv = 1.f + wu.f + wd.f + wl.f + wr.f;                \
        const float av = kv * xc.f - wu.f * xu.f - wd.f * xd.f           \
                         - wl.f * xl.f - wr.f * xr.f;                    \
        out.f = xc.f + ta * (bv.f - av); }
      ELEM(x) ELEM(y) ELEM(z) ELEM(w)
#undef ELEM
    }
    if (c4 == 0)   x1[rr][3]   = 0.f;    // left edge pad (read as .w below)
    if (c4 == 508) x1[rr][516] = 0.f;    // right edge pad (read as .x below)
    *(float4*)&x1[rr][4 + c4] = out;
  }
  __syncthreads();

  // ---- step 2: x2 on rows y0 .. y0+7 from LDS -> global ----
  for (int idx = tid; idx < STRIP * 128; idx += 256) {
    const int rr = idx >> 7;             // 0..7
    const int c4 = (idx & 127) << 2;
    const int y  = y0 + rr;
    const int l  = rr + 1;               // LDS row of x1[y]
    const int t  = y * W + c4;

    const float4 xc = *(const float4*)&x1[l][4 + c4];
    const float4 xu = *(const float4*)&x1[l - 1][4 + c4];  // zero row if y==0
    const float4 xd = *(const float4*)&x1[l + 1][4 + c4];  // zero row if y==H-1
    const float4 l4 = *(const float4*)&x1[l][c4];          // aligned; use .w
    const float4 r4 = *(const float4*)&x1[l][8 + c4];      // aligned; use .x
    const float4 xl = make_float4(l4.w, xc.x, xc.y, xc.z);
    const float4 xr = make_float4(xc.y, xc.z, xc.w, r4.x);

    const float4 bv = *(const float4*)(bp + t);
    float4 wu = make_float4(0.f,0.f,0.f,0.f), wd = wu;
    if (y > 0)     wu = *(const float4*)(wcb + t - W);
    if (y < H - 1) wd = *(const float4*)(wcb + t);
    const float* wrow = wrb + (size_t)y * WRROW;
    const float wl0 = (c4 > 0) ? wrow[c4 - 1] : 0.f;
    const float w0 = wrow[c4], w1 = wrow[c4 + 1], w2 = wrow[c4 + 2];
    const float w3 = (c4 + 3 < W - 1) ? wrow[c4 + 3] : 0.f;
    const float4 wl = make_float4(wl0, w0, w1, w2);
    const float4 wr = make_float4(w0, w1, w2, w3);

    float4 out;
#define ELEM(f) {                                                        \
      const float kv = 1.f + wu.f + wd.f + wl.f + wr.f;                  \
      const float av = kv * xc.f - wu.f * xu.f - wd.f * xd.f             \
                       - wl.f * xl.f - wr.f * xr.f;                      \
      out.f = xc.f + tb * (bv.f - av); }
    ELEM(x) ELEM(y) ELEM(z) ELEM(w)
#undef ELEM
    *(float4*)(XD + (size_t)j * S + t) = out;
  }
}

extern "C" void kernel_launch(void* const* d_in, const int* in_sizes, int n_in,
                              void* d_out, int out_size, void* d_ws, size_t ws_size,
                              hipStream_t stream) {
  const float* Bp = (const float*)d_in[0];
  const float* WC = (const float*)d_in[1];
  const float* WR = (const float*)d_in[2];
  float* Xout = (float*)d_out;
  float* bufA = (float*)d_ws;          // 50 MB ping buffer

  // 12 Chebyshev nodes on [1,9] (theta=5, delta=4); residual poly max
  // 1/T_12(1.25) ~= 9.8e-4. Conjugate-pair order, larger-lambda node first
  // within each pair -> bounded intermediates, fp32-stable.
  const int ord[12] = {1,12, 6,7, 3,10, 4,9, 2,11, 5,8};
  float tau[12];
  for (int i = 0; i < 12; ++i) {
    const double lam = 5.0 + 4.0 * cos(M_PI * (2.0 * ord[i] - 1.0) / 24.0);
    tau[i] = (float)(1.0 / lam);
  }

  dim3 grid(H / STRIP, NP), block(256);
  const float* src = Bp;               // x_0 = B
  for (int i = 0; i < 6; ++i) {
    float* dst = (i & 1) ? Xout : bufA;            // i=5 -> Xout holds x_12
    cheb2<<<grid, block, 0, stream>>>(src, dst, Bp, WC, WR,
                                      tau[2 * i], tau[2 * i + 1]);
    src = dst;
  }
}